// Round 1
// baseline (289.924 us; speedup 1.0000x reference)
//
#include <hip/hip_runtime.h>
#include <hip/hip_cooperative_groups.h>

namespace cg = cooperative_groups;

#define NDIM 2048
#define KD 512
#define DD 64
#define LSTR 72   // mainkern LDS row stride in bf16 (144 B): 16B-aligned, bank-balanced

typedef short bf16x8 __attribute__((ext_vector_type(8)));
typedef float f32x4  __attribute__((ext_vector_type(4)));

__device__ __forceinline__ float sigf(float x) {
    return __builtin_amdgcn_rcpf(1.0f + __builtin_amdgcn_exp2f(x * -1.44269504088896f));
}
__device__ __forceinline__ unsigned short f2bf(float f) {
    union { float f; unsigned u; } c; c.f = f;
    unsigned r = c.u + 0x7FFF + ((c.u >> 16) & 1);   // RNE
    return (unsigned short)(r >> 16);
}

// ---------------------------------------------------------------------------
// fused: single cooperative kernel, 1024 blocks x 256 threads.
//   phase 1 (blocks 0..511): zkern body — 4 rows/block, split-K(4).
//   grid.sync()
//   phase 2 (all 1024 blocks): mainkern body — one 64x64 output tile each.
// LDS overlaid between phases (phase1: 11.8 KB, phase2: 18.9 KB).
// __launch_bounds__(256,4): <=128 VGPR -> 4 blocks/CU -> exactly 1024 resident.
// ---------------------------------------------------------------------------
#define SMEM_BYTES 18976

__global__ __launch_bounds__(256, 4) void fused(
    const float* __restrict__ x, const float* __restrict__ W,
    const float* __restrict__ W2, const float* __restrict__ W3,
    float* __restrict__ A, float* __restrict__ Bv,
    unsigned short* __restrict__ Zb, unsigned short* __restrict__ ZWb,
    float* __restrict__ out)
{
    __shared__ __align__(16) char smem[SMEM_BYTES];
    const int t = threadIdx.x;

    // ---------------- phase 1: z = x@W, A, Bv, Zb, ZWb (blocks 0..511) -----
    if (blockIdx.x < 512) {
        float4* xs4  = (float4*)smem;                // 4*128 float4 = 8192 B
        float*  us   = (float*)(smem + 8192);        // 64 f32
        float*  vs   = (float*)(smem + 8448);        // 64 f32
        float4* part = (float4*)(smem + 8704);       // 3*64 float4 = 3072 B
        const int i0 = blockIdx.x * 4;

        // u = W2[:64]@w3a (wave0), v = W2[64:]@w3a (wave1)
        if (t < 128) {
            const int k = t & 63;
            const float* wrow = W2 + (size_t)(t < 64 ? k : 64 + k) * 64;
            float s = 0.f;
            #pragma unroll
            for (int n4 = 0; n4 < 16; ++n4) {
                float4 a = ((const float4*)wrow)[n4];
                float4 b = ((const float4*)W3)[n4];
                s += a.x * b.x + a.y * b.y + a.z * b.z + a.w * b.w;
            }
            if (t < 64) us[k] = s; else vs[k] = s;
        }

        // stage x tile (4 x 512 f32, coalesced float4)
        #pragma unroll
        for (int ch = 0; ch < 2; ++ch) {
            int idx = ch * 256 + t;              // 0..511
            int row = idx >> 7, c4 = idx & 127;
            xs4[row * 128 + c4] = ((const float4*)(x + (size_t)(i0 + row) * KD))[c4];
        }
        __syncthreads();

        const int tx = t & 15, rw = (t >> 4) & 3, kh = t >> 6;   // kh wave-uniform
        const int c = tx * 4;
        float4 acc = {0.f, 0.f, 0.f, 0.f};
        const float* xrow = (const float*)xs4 + rw * KD + kh * 128;
        const float* Wp   = W + (size_t)(kh * 128) * DD + c;
        #pragma unroll 8
        for (int k = 0; k < 128; ++k) {
            float  xv = xrow[k];                                   // LDS broadcast
            float4 wv = *(const float4*)(Wp + (size_t)k * DD);     // L1-resident
            acc.x += xv * wv.x; acc.y += xv * wv.y;
            acc.z += xv * wv.z; acc.w += xv * wv.w;
        }
        if (kh) part[(kh - 1) * 64 + rw * 16 + tx] = acc;
        __syncthreads();

        if (t < 64) {
            float4 p0 = part[t], p1 = part[64 + t], p2 = part[128 + t];
            acc.x += p0.x + p1.x + p2.x;
            acc.y += p0.y + p1.y + p2.y;
            acc.z += p0.z + p1.z + p2.z;
            acc.w += p0.w + p1.w + p2.w;
            const int row = i0 + rw;

            union { unsigned short s[4]; uint2 v; } zb, zwb;
            zb.s[0] = f2bf(acc.x); zb.s[1] = f2bf(acc.y);
            zb.s[2] = f2bf(acc.z); zb.s[3] = f2bf(acc.w);
            *(uint2*)(Zb + (size_t)row * DD + c) = zb.v;

            float4 w3b = *(const float4*)(W3 + DD + c);
            zwb.s[0] = f2bf(acc.x * w3b.x); zwb.s[1] = f2bf(acc.y * w3b.y);
            zwb.s[2] = f2bf(acc.z * w3b.z); zwb.s[3] = f2bf(acc.w * w3b.w);
            *(uint2*)(ZWb + (size_t)row * DD + c) = zwb.v;

            float4 rz = {fmaxf(acc.x, 0.f), fmaxf(acc.y, 0.f),
                         fmaxf(acc.z, 0.f), fmaxf(acc.w, 0.f)};
            float4 u4 = *(const float4*)(us + c);
            float4 v4 = *(const float4*)(vs + c);
            float pa = rz.x * u4.x + rz.y * u4.y + rz.z * u4.z + rz.w * u4.w;
            float pb = rz.x * v4.x + rz.y * v4.y + rz.z * v4.z + rz.w * v4.w;
            #pragma unroll
            for (int m = 1; m < 16; m <<= 1) {    // reduce within 16-lane groups
                pa += __shfl_xor(pa, m, 64);
                pb += __shfl_xor(pb, m, 64);
            }
            if (tx == 0) { A[row] = pa; Bv[row] = pb; }
        }
    }

    __threadfence();            // make Zb/ZWb/A/Bv device-visible (cross-XCD)
    cg::this_grid().sync();

    // ---------------- phase 2: 64x64 output tile per block -----------------
    {
        unsigned short* sZ = (unsigned short*)smem;            // 64*72+8 bf16
        unsigned short* sW = (unsigned short*)(smem + 9232);   // 64*72+8 bf16
        float* sA = (float*)(smem + 18464);
        float* sB = (float*)(smem + 18720);
        const int i0 = (int)(blockIdx.x >> 5) * 64;
        const int j0 = (int)(blockIdx.x & 31) * 64;

        if (t < 64)       sA[t]      = A[i0 + t];
        else if (t < 128) sB[t - 64] = Bv[j0 + t - 64];

        // stage 64x64 bf16 tiles, stride-72 padded (bank-balanced b128 writes)
        #pragma unroll
        for (int ch = 0; ch < 2; ++ch) {
            int idx = ch * 256 + t;              // 0..511
            int row = idx >> 3, c8 = idx & 7;    // 8 x 16B chunks per row
            uint4 g = ((const uint4*)(Zb  + (size_t)(i0 + row) * DD))[c8];
            *(uint4*)(sZ + row * LSTR + c8 * 8) = g;
            uint4 h = ((const uint4*)(ZWb + (size_t)(j0 + row) * DD))[c8];
            *(uint4*)(sW + row * LSTR + c8 * 8) = h;
        }
        __syncthreads();

        const int lane = t & 63, w = t >> 6;     // wave w owns rows 16w..16w+15
        const int m = lane & 15, quad = lane >> 4;

        // A frags: A[m][k=quad*8+j], two K-chunks (0..31, 32..63)
        bf16x8 a0 = *(const bf16x8*)(sZ + (16 * w + m) * LSTR + quad * 8);
        bf16x8 a1 = *(const bf16x8*)(sZ + (16 * w + m) * LSTR + 32 + quad * 8);

        f32x4 acc[4];
        #pragma unroll
        for (int t4 = 0; t4 < 4; ++t4) {
            bf16x8 b0 = *(const bf16x8*)(sW + (16 * t4 + m) * LSTR + quad * 8);
            bf16x8 b1 = *(const bf16x8*)(sW + (16 * t4 + m) * LSTR + 32 + quad * 8);
            f32x4 c = {0.f, 0.f, 0.f, 0.f};
            c = __builtin_amdgcn_mfma_f32_16x16x32_bf16(a0, b0, c, 0, 0, 0);
            c = __builtin_amdgcn_mfma_f32_16x16x32_bf16(a1, b1, c, 0, 0, 0);
            acc[t4] = c;
        }

        // epilogue: C layout col=lane&15, row=quad*4+reg; nt streaming stores
        #pragma unroll
        for (int t4 = 0; t4 < 4; ++t4) {
            const int j   = j0 + 16 * t4 + m;
            const float bj = sB[16 * t4 + m];
            float* op = out + (size_t)(i0 + 16 * w + quad * 4) * NDIM + j;
            #pragma unroll
            for (int r = 0; r < 4; ++r) {
                const float ab = sA[16 * w + quad * 4 + r] + bj;
                float s  = ab + acc[t4][r];
                float y  = sigf(s);                       // inner sigmoid, exact
                float tt = y - 0.5f;                      // outer: cubic Taylor
                float o  = 0.6224593f +
                           tt * (0.2350037f + tt * (-0.0287786f + tt * (-0.0160594f)));
                __builtin_nontemporal_store(o, op);
                op += NDIM;
            }
        }
    }
}

// ---------------------------------------------------------------------------
// Fallback path (original two-kernel version) in case cooperative launch is
// rejected under graph capture. Numerically identical.
// ---------------------------------------------------------------------------
__global__ __launch_bounds__(256) void zkern(
    const float* __restrict__ x, const float* __restrict__ W,
    const float* __restrict__ W2, const float* __restrict__ W3,
    float* __restrict__ A, float* __restrict__ Bv,
    unsigned short* __restrict__ Zb, unsigned short* __restrict__ ZWb)
{
    __shared__ float4 xs4[4 * 128];
    __shared__ float  us[64], vs[64];
    __shared__ float4 part[3 * 64];
    const int t  = threadIdx.x;
    const int i0 = blockIdx.x * 4;

    if (t < 128) {
        const int k = t & 63;
        const float* wrow = W2 + (size_t)(t < 64 ? k : 64 + k) * 64;
        float s = 0.f;
        #pragma unroll
        for (int n4 = 0; n4 < 16; ++n4) {
            float4 a = ((const float4*)wrow)[n4];
            float4 b = ((const float4*)W3)[n4];
            s += a.x * b.x + a.y * b.y + a.z * b.z + a.w * b.w;
        }
        if (t < 64) us[k] = s; else vs[k] = s;
    }

    #pragma unroll
    for (int ch = 0; ch < 2; ++ch) {
        int idx = ch * 256 + t;
        int row = idx >> 7, c4 = idx & 127;
        xs4[row * 128 + c4] = ((const float4*)(x + (size_t)(i0 + row) * KD))[c4];
    }
    __syncthreads();

    const int tx = t & 15, rw = (t >> 4) & 3, kh = t >> 6;
    const int c = tx * 4;
    float4 acc = {0.f, 0.f, 0.f, 0.f};
    const float* xrow = (const float*)xs4 + rw * KD + kh * 128;
    const float* Wp   = W + (size_t)(kh * 128) * DD + c;
    #pragma unroll 8
    for (int k = 0; k < 128; ++k) {
        float  xv = xrow[k];
        float4 wv = *(const float4*)(Wp + (size_t)k * DD);
        acc.x += xv * wv.x; acc.y += xv * wv.y;
        acc.z += xv * wv.z; acc.w += xv * wv.w;
    }
    if (kh) part[(kh - 1) * 64 + rw * 16 + tx] = acc;
    __syncthreads();

    if (t < 64) {
        float4 p0 = part[t], p1 = part[64 + t], p2 = part[128 + t];
        acc.x += p0.x + p1.x + p2.x;
        acc.y += p0.y + p1.y + p2.y;
        acc.z += p0.z + p1.z + p2.z;
        acc.w += p0.w + p1.w + p2.w;
        const int row = i0 + rw;

        union { unsigned short s[4]; uint2 v; } zb, zwb;
        zb.s[0] = f2bf(acc.x); zb.s[1] = f2bf(acc.y);
        zb.s[2] = f2bf(acc.z); zb.s[3] = f2bf(acc.w);
        *(uint2*)(Zb + (size_t)row * DD + c) = zb.v;

        float4 w3b = *(const float4*)(W3 + DD + c);
        zwb.s[0] = f2bf(acc.x * w3b.x); zwb.s[1] = f2bf(acc.y * w3b.y);
        zwb.s[2] = f2bf(acc.z * w3b.z); zwb.s[3] = f2bf(acc.w * w3b.w);
        *(uint2*)(ZWb + (size_t)row * DD + c) = zwb.v;

        float4 rz = {fmaxf(acc.x, 0.f), fmaxf(acc.y, 0.f),
                     fmaxf(acc.z, 0.f), fmaxf(acc.w, 0.f)};
        float4 u4 = *(const float4*)(us + c);
        float4 v4 = *(const float4*)(vs + c);
        float pa = rz.x * u4.x + rz.y * u4.y + rz.z * u4.z + rz.w * u4.w;
        float pb = rz.x * v4.x + rz.y * v4.y + rz.z * v4.z + rz.w * v4.w;
        #pragma unroll
        for (int m = 1; m < 16; m <<= 1) {
            pa += __shfl_xor(pa, m, 64);
            pb += __shfl_xor(pb, m, 64);
        }
        if (tx == 0) { A[row] = pa; Bv[row] = pb; }
    }
}

__global__ __launch_bounds__(256) void mainkern(
    const unsigned short* __restrict__ Zb, const unsigned short* __restrict__ ZWb,
    const float* __restrict__ A, const float* __restrict__ Bv,
    float* __restrict__ out)
{
    __shared__ unsigned short sZ[64 * LSTR + 8];
    __shared__ unsigned short sW[64 * LSTR + 8];
    __shared__ float sA[64], sB[64];
    const int t  = threadIdx.x;
    const int i0 = blockIdx.y * 64, j0 = blockIdx.x * 64;

    if (t < 64)       sA[t]      = A[i0 + t];
    else if (t < 128) sB[t - 64] = Bv[j0 + t - 64];

    #pragma unroll
    for (int ch = 0; ch < 2; ++ch) {
        int idx = ch * 256 + t;
        int row = idx >> 3, c8 = idx & 7;
        uint4 g = ((const uint4*)(Zb  + (size_t)(i0 + row) * DD))[c8];
        *(uint4*)(sZ + row * LSTR + c8 * 8) = g;
        uint4 h = ((const uint4*)(ZWb + (size_t)(j0 + row) * DD))[c8];
        *(uint4*)(sW + row * LSTR + c8 * 8) = h;
    }
    __syncthreads();

    const int lane = t & 63, w = t >> 6;
    const int m = lane & 15, quad = lane >> 4;

    bf16x8 a0 = *(const bf16x8*)(sZ + (16 * w + m) * LSTR + quad * 8);
    bf16x8 a1 = *(const bf16x8*)(sZ + (16 * w + m) * LSTR + 32 + quad * 8);

    f32x4 acc[4];
    #pragma unroll
    for (int t4 = 0; t4 < 4; ++t4) {
        bf16x8 b0 = *(const bf16x8*)(sW + (16 * t4 + m) * LSTR + quad * 8);
        bf16x8 b1 = *(const bf16x8*)(sW + (16 * t4 + m) * LSTR + 32 + quad * 8);
        f32x4 c = {0.f, 0.f, 0.f, 0.f};
        c = __builtin_amdgcn_mfma_f32_16x16x32_bf16(a0, b0, c, 0, 0, 0);
        c = __builtin_amdgcn_mfma_f32_16x16x32_bf16(a1, b1, c, 0, 0, 0);
        acc[t4] = c;
    }

    #pragma unroll
    for (int t4 = 0; t4 < 4; ++t4) {
        const int j   = j0 + 16 * t4 + m;
        const float bj = sB[16 * t4 + m];
        float* op = out + (size_t)(i0 + 16 * w + quad * 4) * NDIM + j;
        #pragma unroll
        for (int r = 0; r < 4; ++r) {
            const float ab = sA[16 * w + quad * 4 + r] + bj;
            float s  = ab + acc[t4][r];
            float y  = sigf(s);
            float tt = y - 0.5f;
            float o  = 0.6224593f +
                       tt * (0.2350037f + tt * (-0.0287786f + tt * (-0.0160594f)));
            __builtin_nontemporal_store(o, op);
            op += NDIM;
        }
    }
}

extern "C" void kernel_launch(void* const* d_in, const int* in_sizes, int n_in,
                              void* d_out, int out_size, void* d_ws, size_t ws_size,
                              hipStream_t stream)
{
    const float* x  = (const float*)d_in[0];   // 2048 x 512
    const float* W  = (const float*)d_in[1];   // 512 x 64
    const float* W2 = (const float*)d_in[2];   // 128 x 64
    const float* W3 = (const float*)d_in[3];   // 128 x 1
    float* out = (float*)d_out;                // 2048 x 2048 f32

    char* ws = (char*)d_ws;
    float* A  = (float*)ws;                              // 2048 f32
    float* Bv = (float*)(ws + 8192);                     // 2048 f32
    unsigned short* Zb  = (unsigned short*)(ws + 16384);               // 2048x64 bf16
    unsigned short* ZWb = (unsigned short*)(ws + 16384 + NDIM * DD * 2);

    void* kargs[] = {(void*)&x, (void*)&W, (void*)&W2, (void*)&W3,
                     (void*)&A, (void*)&Bv, (void*)&Zb, (void*)&ZWb, (void*)&out};
    hipError_t err = hipLaunchCooperativeKernel(
        fused, dim3(1024), dim3(256), kargs, (unsigned int)0, stream);
    if (err != hipSuccess) {
        // fallback: original two-kernel path (identical numerics)
        zkern<<<dim3(512), dim3(256), 0, stream>>>(x, W, W2, W3, A, Bv, Zb, ZWb);
        mainkern<<<dim3(32, 32), dim3(256), 0, stream>>>(Zb, ZWb, A, Bv, out);
    }
}

// Round 2
// 80.366 us; speedup vs baseline: 3.6076x; 3.6076x over previous
//
#include <hip/hip_runtime.h>

#define NDIM 2048
#define KD 512
#define DD 64
#define LSTR 72   // mainkern LDS row stride in bf16 (144 B): 16B-aligned, bank-balanced

typedef short bf16x8 __attribute__((ext_vector_type(8)));
typedef float f32x4  __attribute__((ext_vector_type(4)));

__device__ __forceinline__ float sigf(float x) {
    return __builtin_amdgcn_rcpf(1.0f + __builtin_amdgcn_exp2f(x * -1.44269504088896f));
}
__device__ __forceinline__ unsigned short f2bf(float f) {
    union { float f; unsigned u; } c; c.f = f;
    unsigned r = c.u + 0x7FFF + ((c.u >> 16) & 1);   // RNE
    return (unsigned short)(r >> 16);
}

// ---------------------------------------------------------------------------
// zkern: 512 blocks x 256 threads, 4 rows/block, split-K(4).
// 2 blocks/CU -> 8 waves/CU for latency hiding; W quarter (32KB) fits L1.
// Emits A=relu(z)@u, Bv=relu(z)@v (f32), Zb=bf16(z), ZWb=bf16(z*w3b).
// ---------------------------------------------------------------------------
__global__ __launch_bounds__(256) void zkern(
    const float* __restrict__ x, const float* __restrict__ W,
    const float* __restrict__ W2, const float* __restrict__ W3,
    float* __restrict__ A, float* __restrict__ Bv,
    unsigned short* __restrict__ Zb, unsigned short* __restrict__ ZWb)
{
    __shared__ float4 xs4[4 * 128];          // 4 rows x 512 f32 = 8 KB
    __shared__ float  us[64], vs[64];
    __shared__ float4 part[3 * 64];          // split-K partials for kh=1..3
    const int t  = threadIdx.x;
    const int i0 = blockIdx.x * 4;

    // u = W2[:64]@w3a (wave0), v = W2[64:]@w3a (wave1)
    if (t < 128) {
        const int k = t & 63;
        const float* wrow = W2 + (size_t)(t < 64 ? k : 64 + k) * 64;
        float s = 0.f;
        #pragma unroll
        for (int n4 = 0; n4 < 16; ++n4) {
            float4 a = ((const float4*)wrow)[n4];
            float4 b = ((const float4*)W3)[n4];
            s += a.x * b.x + a.y * b.y + a.z * b.z + a.w * b.w;
        }
        if (t < 64) us[k] = s; else vs[k] = s;
    }

    // stage x tile (4 x 512 f32, coalesced float4)
    #pragma unroll
    for (int ch = 0; ch < 2; ++ch) {
        int idx = ch * 256 + t;              // 0..511
        int row = idx >> 7, c4 = idx & 127;
        xs4[row * 128 + c4] = ((const float4*)(x + (size_t)(i0 + row) * KD))[c4];
    }
    __syncthreads();

    const int tx = t & 15, rw = (t >> 4) & 3, kh = t >> 6;   // kh wave-uniform
    const int c = tx * 4;
    float4 acc = {0.f, 0.f, 0.f, 0.f};
    const float* xrow = (const float*)xs4 + rw * KD + kh * 128;
    const float* Wp   = W + (size_t)(kh * 128) * DD + c;
    #pragma unroll 8
    for (int k = 0; k < 128; ++k) {
        float  xv = xrow[k];                                   // LDS broadcast
        float4 wv = *(const float4*)(Wp + (size_t)k * DD);     // L1-resident
        acc.x += xv * wv.x; acc.y += xv * wv.y;
        acc.z += xv * wv.z; acc.w += xv * wv.w;
    }
    if (kh) part[(kh - 1) * 64 + rw * 16 + tx] = acc;
    __syncthreads();

    if (t < 64) {
        float4 p0 = part[t], p1 = part[64 + t], p2 = part[128 + t];
        acc.x += p0.x + p1.x + p2.x;
        acc.y += p0.y + p1.y + p2.y;
        acc.z += p0.z + p1.z + p2.z;
        acc.w += p0.w + p1.w + p2.w;
        const int row = i0 + rw;

        union { unsigned short s[4]; uint2 v; } zb, zwb;
        zb.s[0] = f2bf(acc.x); zb.s[1] = f2bf(acc.y);
        zb.s[2] = f2bf(acc.z); zb.s[3] = f2bf(acc.w);
        *(uint2*)(Zb + (size_t)row * DD + c) = zb.v;

        float4 w3b = *(const float4*)(W3 + DD + c);
        zwb.s[0] = f2bf(acc.x * w3b.x); zwb.s[1] = f2bf(acc.y * w3b.y);
        zwb.s[2] = f2bf(acc.z * w3b.z); zwb.s[3] = f2bf(acc.w * w3b.w);
        *(uint2*)(ZWb + (size_t)row * DD + c) = zwb.v;

        float4 rz = {fmaxf(acc.x, 0.f), fmaxf(acc.y, 0.f),
                     fmaxf(acc.z, 0.f), fmaxf(acc.w, 0.f)};
        float4 u4 = *(const float4*)(us + c);
        float4 v4 = *(const float4*)(vs + c);
        float pa = rz.x * u4.x + rz.y * u4.y + rz.z * u4.z + rz.w * u4.w;
        float pb = rz.x * v4.x + rz.y * v4.y + rz.z * v4.z + rz.w * v4.w;
        #pragma unroll
        for (int m = 1; m < 16; m <<= 1) {    // reduce within 16-lane groups
            pa += __shfl_xor(pa, m, 64);
            pb += __shfl_xor(pb, m, 64);
        }
        if (tx == 0) { A[row] = pa; Bv[row] = pb; }
    }
}

// ---------------------------------------------------------------------------
// mainkern: grid (32,32) x 256 threads; 64x64 tile/block via bf16 MFMA.
// out[i,j] = sig(sig(A[i] + Bv[j] + Zb[i,:]·ZWb[j,:])). Outer sigmoid as
// cubic Taylor (input confined to (0,1), max err ~3e-4). HBM-write-bound;
// output streamed with non-temporal stores (write-once, keep L2 for Zb/ZWb).
// ---------------------------------------------------------------------------
__global__ __launch_bounds__(256) void mainkern(
    const unsigned short* __restrict__ Zb, const unsigned short* __restrict__ ZWb,
    const float* __restrict__ A, const float* __restrict__ Bv,
    float* __restrict__ out)
{
    __shared__ unsigned short sZ[64 * LSTR + 8];
    __shared__ unsigned short sW[64 * LSTR + 8];
    __shared__ float sA[64], sB[64];
    const int t  = threadIdx.x;
    const int i0 = blockIdx.y * 64, j0 = blockIdx.x * 64;

    if (t < 64)       sA[t]      = A[i0 + t];
    else if (t < 128) sB[t - 64] = Bv[j0 + t - 64];

    // stage 64x64 bf16 tiles, stride-72 padded (bank-balanced b128 writes)
    #pragma unroll
    for (int ch = 0; ch < 2; ++ch) {
        int idx = ch * 256 + t;              // 0..511
        int row = idx >> 3, c8 = idx & 7;    // 8 x 16B chunks per row
        uint4 g = ((const uint4*)(Zb  + (size_t)(i0 + row) * DD))[c8];
        *(uint4*)(sZ + row * LSTR + c8 * 8) = g;
        uint4 h = ((const uint4*)(ZWb + (size_t)(j0 + row) * DD))[c8];
        *(uint4*)(sW + row * LSTR + c8 * 8) = h;
    }
    __syncthreads();

    const int lane = t & 63, w = t >> 6;     // wave w owns rows 16w..16w+15
    const int m = lane & 15, quad = lane >> 4;

    // A frags: A[m][k=quad*8+j], two K-chunks (0..31, 32..63)
    bf16x8 a0 = *(const bf16x8*)(sZ + (16 * w + m) * LSTR + quad * 8);
    bf16x8 a1 = *(const bf16x8*)(sZ + (16 * w + m) * LSTR + 32 + quad * 8);

    f32x4 acc[4];
    #pragma unroll
    for (int t4 = 0; t4 < 4; ++t4) {
        bf16x8 b0 = *(const bf16x8*)(sW + (16 * t4 + m) * LSTR + quad * 8);
        bf16x8 b1 = *(const bf16x8*)(sW + (16 * t4 + m) * LSTR + 32 + quad * 8);
        f32x4 c = {0.f, 0.f, 0.f, 0.f};
        c = __builtin_amdgcn_mfma_f32_16x16x32_bf16(a0, b0, c, 0, 0, 0);
        c = __builtin_amdgcn_mfma_f32_16x16x32_bf16(a1, b1, c, 0, 0, 0);
        acc[t4] = c;
    }

    // epilogue: C layout col=lane&15, row=quad*4+reg; nt streaming stores
    #pragma unroll
    for (int t4 = 0; t4 < 4; ++t4) {
        const int j   = j0 + 16 * t4 + m;
        const float bj = sB[16 * t4 + m];
        float* op = out + (size_t)(i0 + 16 * w + quad * 4) * NDIM + j;
        #pragma unroll
        for (int r = 0; r < 4; ++r) {
            const float ab = sA[16 * w + quad * 4 + r] + bj;
            float s  = ab + acc[t4][r];
            float y  = sigf(s);                       // inner sigmoid, exact
            float tt = y - 0.5f;                      // outer: cubic Taylor
            float o  = 0.6224593f +
                       tt * (0.2350037f + tt * (-0.0287786f + tt * (-0.0160594f)));
            __builtin_nontemporal_store(o, op);
            op += NDIM;
        }
    }
}

extern "C" void kernel_launch(void* const* d_in, const int* in_sizes, int n_in,
                              void* d_out, int out_size, void* d_ws, size_t ws_size,
                              hipStream_t stream)
{
    const float* x  = (const float*)d_in[0];   // 2048 x 512
    const float* W  = (const float*)d_in[1];   // 512 x 64
    const float* W2 = (const float*)d_in[2];   // 128 x 64
    const float* W3 = (const float*)d_in[3];   // 128 x 1
    float* out = (float*)d_out;                // 2048 x 2048 f32

    char* ws = (char*)d_ws;
    float* A  = (float*)ws;                              // 2048 f32
    float* Bv = (float*)(ws + 8192);                     // 2048 f32
    unsigned short* Zb  = (unsigned short*)(ws + 16384);               // 2048x64 bf16
    unsigned short* ZWb = (unsigned short*)(ws + 16384 + NDIM * DD * 2);

    zkern<<<dim3(512), dim3(256), 0, stream>>>(x, W, W2, W3, A, Bv, Zb, ZWb);
    mainkern<<<dim3(32, 32), dim3(256), 0, stream>>>(Zb, ZWb, A, Bv, out);
}